// Round 1
// baseline (484.451 us; speedup 1.0000x reference)
//
#include <hip/hip_runtime.h>
#include <hip/hip_bf16.h>
#include <stdint.h>

#define T_TOK 4096
#define H_DIM 1024
#define F_DIM 2816
#define NE 8
#define NPAIR (T_TOK * 2)

using bf16x8 = __attribute__((ext_vector_type(8))) short;   // 8 bf16 in 4 VGPRs
using f32x4  = __attribute__((ext_vector_type(4))) float;   // MFMA accumulator

// RNE float -> bf16 bits (finite inputs only)
__device__ __forceinline__ unsigned short f2bf(float f) {
    union { float f; uint32_t u; } v; v.f = f;
    uint32_t r = v.u + 0x7FFFu + ((v.u >> 16) & 1u);
    return (unsigned short)(r >> 16);
}

// async global->LDS, 16B per lane. lds must be wave-uniform base; HW writes base + lane*16.
__device__ __forceinline__ void gload_lds16(const void* gsrc, void* lds) {
    __builtin_amdgcn_global_load_lds(
        (const __attribute__((address_space(1))) uint32_t*)gsrc,
        (__attribute__((address_space(3))) uint32_t*)lds, 16, 0, 0);
}

// ---------------- router: one wave per token ----------------
__global__ __launch_bounds__(256) void router_kernel(
    const float* __restrict__ x, const float* __restrict__ wr,
    int* __restrict__ top_i, float* __restrict__ top_w, int* __restrict__ counts)
{
    const int w = threadIdx.x >> 6, l = threadIdx.x & 63;
    const int tok = blockIdx.x * 4 + w;
    const float* xrow = x + (size_t)tok * H_DIM;
    float acc[NE] = {};
    for (int h = l; h < H_DIM; h += 64) {
        float xv = xrow[h];
        const float* wrow = wr + h * NE;
#pragma unroll
        for (int e = 0; e < NE; e++) acc[e] += xv * wrow[e];
    }
#pragma unroll
    for (int e = 0; e < NE; e++) {
        for (int off = 32; off; off >>= 1) acc[e] += __shfl_xor(acc[e], off);
    }
    if (l == 0) {
        int i1 = 0; float b1 = acc[0];
#pragma unroll
        for (int e = 1; e < NE; e++) if (acc[e] > b1) { b1 = acc[e]; i1 = e; }
        int i2 = -1; float b2 = -1e30f;
#pragma unroll
        for (int e = 0; e < NE; e++) if (e != i1 && acc[e] > b2) { b2 = acc[e]; i2 = e; }
        // renormalized top-2 softmax weights, exact: p1/(p1+p2) = 1/(1+exp(l2-l1))
        float w1 = 1.0f / (1.0f + __expf(b2 - b1));
        top_i[tok * 2] = i1; top_i[tok * 2 + 1] = i2;
        top_w[tok * 2] = w1; top_w[tok * 2 + 1] = 1.0f - w1;
        atomicAdd(&counts[i1], 1); atomicAdd(&counts[i2], 1);
    }
}

__global__ void prefix_kernel(const int* __restrict__ counts,
                              int* __restrict__ offsets, int* __restrict__ cursor)
{
    if (threadIdx.x == 0 && blockIdx.x == 0) {
        int s = 0;
        for (int e = 0; e < NE; e++) { offsets[e] = s; cursor[e] = s; s += counts[e]; }
        offsets[NE] = s;   // == 8192 always
    }
}

__global__ __launch_bounds__(256) void scatter_kernel(
    const int* __restrict__ top_i, const float* __restrict__ top_w,
    int* __restrict__ cursor, int* __restrict__ pair_tok, float* __restrict__ pair_w)
{
    int tok = blockIdx.x * 256 + threadIdx.x;
    if (tok < T_TOK) {
#pragma unroll
        for (int k = 0; k < 2; k++) {
            int e = top_i[tok * 2 + k];
            int pos = atomicAdd(&cursor[e], 1);
            pair_tok[pos] = tok;
            pair_w[pos] = top_w[tok * 2 + k];
        }
    }
}

// ---------------- x f32 -> bf16 ----------------
__global__ __launch_bounds__(256) void cvt_x_kernel(const float* __restrict__ x,
                                                    unsigned short* __restrict__ xbf)
{
    int i = blockIdx.x * 256 + threadIdx.x;      // 4 floats per thread
    float4 v = ((const float4*)x)[i];
    ushort4 o;
    o.x = f2bf(v.x); o.y = f2bf(v.y); o.z = f2bf(v.z); o.w = f2bf(v.w);
    ((ushort4*)xbf)[i] = o;
}

// ---------------- batched 2D transpose + cvt: in[e][R][C] f32 -> out[e][C][R] bf16 ----------------
__global__ __launch_bounds__(256) void transpose_cvt_kernel(
    const float* __restrict__ in, unsigned short* __restrict__ outp, int R, int C)
{
    __shared__ float tile[32][33];
    const int e = blockIdx.z;
    const float* inp = in + (size_t)e * R * C;
    unsigned short* oute = outp + (size_t)e * R * C;
    const int tx = threadIdx.x & 31, ty = threadIdx.x >> 5;
    const int c0 = blockIdx.x * 32, r0 = blockIdx.y * 32;
#pragma unroll
    for (int i = 0; i < 4; i++) {
        int r = r0 + ty + i * 8;
        tile[ty + i * 8][tx] = inp[(size_t)r * C + c0 + tx];
    }
    __syncthreads();
#pragma unroll
    for (int i = 0; i < 4; i++) {
        int c = c0 + ty + i * 8;
        oute[(size_t)c * R + r0 + tx] = f2bf(tile[tx][ty + i * 8]);
    }
}

// ---------------- GEMM1: A = gathered x rows [pairs][H], B^T = wgT/wuT [F][H] ----------------
// 128x64 tile, fused gate+up, silu(g)*u epilogue -> Abuf bf16 [8192][F]
__global__ __launch_bounds__(256, 2) void gemm1_kernel(
    const unsigned short* __restrict__ xbf,   // [T][H] bf16
    const unsigned short* __restrict__ wgT,   // [E][F][H] bf16
    const unsigned short* __restrict__ wuT,   // [E][F][H] bf16
    const int* __restrict__ pair_tok, const int* __restrict__ offsets,
    unsigned short* __restrict__ Abuf)        // [8192][F] bf16
{
    const int e   = blockIdx.z;
    const int off = offsets[e];
    const int Ne  = offsets[e + 1] - off;
    const int m0  = blockIdx.y * 128;
    if (m0 >= Ne) return;
    const int bn0 = blockIdx.x * 64;

    __shared__ unsigned short sA[128 * 32];
    __shared__ unsigned short sG[64 * 32];
    __shared__ unsigned short sU[64 * 32];

    const int t = threadIdx.x, l = t & 63, w = t >> 6;
    const int lhi = l >> 4, llo = l & 15;
    const int wm = w >> 1, wn = w & 1;

    // A staging: round i covers lds bytes (i*256+t)*16; row=(idx>>2), k-chunk=(idx&3)*8
    const unsigned short* asrc[2];
#pragma unroll
    for (int i = 0; i < 2; i++) {
        int idx = i * 256 + t;
        int row = idx >> 2, chunk = idx & 3;
        int r = m0 + row; if (r > Ne - 1) r = Ne - 1;   // clamp tail rows (masked in epilogue)
        int tok = pair_tok[off + r];
        asrc[i] = xbf + (size_t)tok * H_DIM + chunk * 8;
    }
    unsigned short* ldsA0 = sA + (0 * 256 + (t & 192)) * 8;  // wave-uniform bases
    unsigned short* ldsA1 = sA + (1 * 256 + (t & 192)) * 8;
    unsigned short* ldsG  = sG + (t & 192) * 8;
    unsigned short* ldsU  = sU + (t & 192) * 8;
    const unsigned short* gsrc = wgT + ((size_t)e * F_DIM + bn0 + (t >> 2)) * H_DIM + (t & 3) * 8;
    const unsigned short* usrc = wuT + ((size_t)e * F_DIM + bn0 + (t >> 2)) * H_DIM + (t & 3) * 8;

    f32x4 accG[4][2] = {};
    f32x4 accU[4][2] = {};

    for (int k0 = 0; k0 < H_DIM; k0 += 32) {
        __syncthreads();
        gload_lds16(asrc[0] + k0, ldsA0);
        gload_lds16(asrc[1] + k0, ldsA1);
        gload_lds16(gsrc + k0, ldsG);
        gload_lds16(usrc + k0, ldsU);
        asm volatile("s_waitcnt vmcnt(0)" ::: "memory");
        __syncthreads();

        bf16x8 af[4], gf[2], uf[2];
#pragma unroll
        for (int m = 0; m < 4; m++)
            af[m] = *(const bf16x8*)(sA + (wm * 64 + m * 16 + llo) * 32 + lhi * 8);
#pragma unroll
        for (int n = 0; n < 2; n++) {
            gf[n] = *(const bf16x8*)(sG + (wn * 32 + n * 16 + llo) * 32 + lhi * 8);
            uf[n] = *(const bf16x8*)(sU + (wn * 32 + n * 16 + llo) * 32 + lhi * 8);
        }
#pragma unroll
        for (int m = 0; m < 4; m++)
#pragma unroll
            for (int n = 0; n < 2; n++) {
                accG[m][n] = __builtin_amdgcn_mfma_f32_16x16x32_bf16(af[m], gf[n], accG[m][n], 0, 0, 0);
                accU[m][n] = __builtin_amdgcn_mfma_f32_16x16x32_bf16(af[m], uf[n], accU[m][n], 0, 0, 0);
            }
    }

    // epilogue: a = silu(g)*u, store bf16. C/D layout: col=lane&15, row=(lane>>4)*4+reg
#pragma unroll
    for (int m = 0; m < 4; m++) {
#pragma unroll
        for (int r = 0; r < 4; r++) {
            int grow = m0 + wm * 64 + m * 16 + lhi * 4 + r;
            if (grow < Ne) {
                size_t p = (size_t)(off + grow);
#pragma unroll
                for (int n = 0; n < 2; n++) {
                    float g = accG[m][n][r];
                    float u = accU[m][n][r];
                    float a = g / (1.0f + __expf(-g)) * u;
                    int f = bn0 + wn * 32 + n * 16 + llo;
                    Abuf[p * F_DIM + f] = f2bf(a);
                }
            }
        }
    }
}

// ---------------- GEMM2: A = Abuf [pairs][F], B^T = wdT [E][H][F]; scatter-add into out ----------------
__global__ __launch_bounds__(256, 2) void gemm2_kernel(
    const unsigned short* __restrict__ Abuf,  // [8192][F] bf16
    const unsigned short* __restrict__ wdT,   // [E][H][F] bf16
    const int* __restrict__ pair_tok, const float* __restrict__ pair_w,
    const int* __restrict__ offsets, float* __restrict__ out)
{
    const int e   = blockIdx.z;
    const int off = offsets[e];
    const int Ne  = offsets[e + 1] - off;
    const int m0  = blockIdx.y * 128;
    if (m0 >= Ne) return;
    const int bn0 = blockIdx.x * 128;

    __shared__ unsigned short sA[128 * 32];
    __shared__ unsigned short sB[128 * 32];

    const int t = threadIdx.x, l = t & 63, w = t >> 6;
    const int lhi = l >> 4, llo = l & 15;
    const int wm = w >> 1, wn = w & 1;

    const unsigned short* asrc[2];
    const unsigned short* bsrc[2];
#pragma unroll
    for (int i = 0; i < 2; i++) {
        int idx = i * 256 + t;
        int row = idx >> 2, chunk = idx & 3;
        int r = m0 + row; if (r > Ne - 1) r = Ne - 1;
        asrc[i] = Abuf + (size_t)(off + r) * F_DIM + chunk * 8;
        bsrc[i] = wdT + ((size_t)e * H_DIM + bn0 + row) * F_DIM + chunk * 8;
    }
    unsigned short* ldsA0 = sA + (0 * 256 + (t & 192)) * 8;
    unsigned short* ldsA1 = sA + (1 * 256 + (t & 192)) * 8;
    unsigned short* ldsB0 = sB + (0 * 256 + (t & 192)) * 8;
    unsigned short* ldsB1 = sB + (1 * 256 + (t & 192)) * 8;

    f32x4 acc[4][4] = {};

    for (int k0 = 0; k0 < F_DIM; k0 += 32) {
        __syncthreads();
        gload_lds16(asrc[0] + k0, ldsA0);
        gload_lds16(asrc[1] + k0, ldsA1);
        gload_lds16(bsrc[0] + k0, ldsB0);
        gload_lds16(bsrc[1] + k0, ldsB1);
        asm volatile("s_waitcnt vmcnt(0)" ::: "memory");
        __syncthreads();

        bf16x8 af[4], bfr[4];
#pragma unroll
        for (int m = 0; m < 4; m++)
            af[m] = *(const bf16x8*)(sA + (wm * 64 + m * 16 + llo) * 32 + lhi * 8);
#pragma unroll
        for (int n = 0; n < 4; n++)
            bfr[n] = *(const bf16x8*)(sB + (wn * 64 + n * 16 + llo) * 32 + lhi * 8);
#pragma unroll
        for (int m = 0; m < 4; m++)
#pragma unroll
            for (int n = 0; n < 4; n++)
                acc[m][n] = __builtin_amdgcn_mfma_f32_16x16x32_bf16(af[m], bfr[n], acc[m][n], 0, 0, 0);
    }

#pragma unroll
    for (int m = 0; m < 4; m++) {
#pragma unroll
        for (int r = 0; r < 4; r++) {
            int grow = m0 + wm * 64 + m * 16 + lhi * 4 + r;
            if (grow < Ne) {
                int p = off + grow;
                int tok = pair_tok[p];
                float wgt = pair_w[p];
                float* orow = out + (size_t)tok * H_DIM + bn0 + wn * 64;
#pragma unroll
                for (int n = 0; n < 4; n++)
                    atomicAdd(orow + n * 16 + llo, wgt * acc[m][n][r]);
            }
        }
    }
}

extern "C" void kernel_launch(void* const* d_in, const int* in_sizes, int n_in,
                              void* d_out, int out_size, void* d_ws, size_t ws_size,
                              hipStream_t stream)
{
    const float* x  = (const float*)d_in[0];
    const float* wr = (const float*)d_in[1];
    const float* wg = (const float*)d_in[2];
    const float* wu = (const float*)d_in[3];
    const float* wd = (const float*)d_in[4];
    float* out = (float*)d_out;

    char* ws = (char*)d_ws;
    const size_t WT = (size_t)NE * F_DIM * H_DIM * 2;          // 46,137,344 B
    unsigned short* wgT  = (unsigned short*)(ws);               // reused for wdT after GEMM1
    unsigned short* wuT  = (unsigned short*)(ws + WT);
    unsigned short* Abuf = (unsigned short*)(ws + 2 * WT);      // [8192][F] bf16
    unsigned short* xbf  = (unsigned short*)(ws + 3 * WT);      // 8 MB
    char* misc = ws + 3 * WT + (size_t)T_TOK * H_DIM * 2;
    int*   pair_tok = (int*)(misc);
    float* pair_w   = (float*)(misc + 32768);
    int*   top_i    = (int*)(misc + 65536);
    float* top_w    = (float*)(misc + 98304);
    int*   counts   = (int*)(misc + 131072);
    int*   offsets  = counts + 8;
    int*   cursor   = offsets + 9;
    unsigned short* wdT = wgT;   // alias: wd transpose runs after GEMM1 (stream-serialized)

    hipMemsetAsync(counts, 0, 8 * sizeof(int), stream);
    hipMemsetAsync(out, 0, (size_t)T_TOK * H_DIM * sizeof(float), stream);

    cvt_x_kernel<<<T_TOK * H_DIM / (256 * 4), 256, 0, stream>>>(x, xbf);
    transpose_cvt_kernel<<<dim3(F_DIM / 32, H_DIM / 32, NE), 256, 0, stream>>>(wg, wgT, H_DIM, F_DIM);
    transpose_cvt_kernel<<<dim3(F_DIM / 32, H_DIM / 32, NE), 256, 0, stream>>>(wu, wuT, H_DIM, F_DIM);
    router_kernel<<<T_TOK / 4, 256, 0, stream>>>(x, wr, top_i, top_w, counts);
    prefix_kernel<<<1, 64, 0, stream>>>(counts, offsets, cursor);
    scatter_kernel<<<T_TOK / 256, 256, 0, stream>>>(top_i, top_w, cursor, pair_tok, pair_w);
    gemm1_kernel<<<dim3(F_DIM / 64, T_TOK / 128, NE), 256, 0, stream>>>(xbf, wgT, wuT, pair_tok, offsets, Abuf);
    transpose_cvt_kernel<<<dim3(H_DIM / 32, F_DIM / 32, NE), 256, 0, stream>>>(wd, wdT, F_DIM, H_DIM);
    gemm2_kernel<<<dim3(H_DIM / 128, T_TOK / 128, NE), 256, 0, stream>>>(Abuf, wdT, pair_tok, pair_w, offsets, out);
}

// Round 2
// 466.484 us; speedup vs baseline: 1.0385x; 1.0385x over previous
//
#include <hip/hip_runtime.h>
#include <hip/hip_bf16.h>
#include <stdint.h>

#define T_TOK 4096
#define H_DIM 1024
#define F_DIM 2816
#define NE 8

using bf16x8 = __attribute__((ext_vector_type(8))) short;   // 8 bf16 in 4 VGPRs
using f32x4  = __attribute__((ext_vector_type(4))) float;   // MFMA accumulator

// RNE float -> bf16 bits (finite inputs only)
__device__ __forceinline__ unsigned short f2bf(float f) {
    union { float f; uint32_t u; } v; v.f = f;
    uint32_t r = v.u + 0x7FFFu + ((v.u >> 16) & 1u);
    return (unsigned short)(r >> 16);
}

// async global->LDS, 16B per lane. lds dest: wave-uniform base + lane*16.
__device__ __forceinline__ void gload_lds16(const void* gsrc, void* lds) {
    __builtin_amdgcn_global_load_lds(
        (const __attribute__((address_space(1))) uint32_t*)gsrc,
        (__attribute__((address_space(3))) uint32_t*)lds, 16, 0, 0);
}

// ---------------- router: one wave per token ----------------
__global__ __launch_bounds__(256) void router_kernel(
    const float* __restrict__ x, const float* __restrict__ wr,
    int* __restrict__ top_i, float* __restrict__ top_w, int* __restrict__ counts)
{
    const int w = threadIdx.x >> 6, l = threadIdx.x & 63;
    const int tok = blockIdx.x * 4 + w;
    const float* xrow = x + (size_t)tok * H_DIM;
    float acc[NE] = {};
    for (int h = l; h < H_DIM; h += 64) {
        float xv = xrow[h];
        const float* wrow = wr + h * NE;
#pragma unroll
        for (int e = 0; e < NE; e++) acc[e] += xv * wrow[e];
    }
#pragma unroll
    for (int e = 0; e < NE; e++) {
        for (int off = 32; off; off >>= 1) acc[e] += __shfl_xor(acc[e], off);
    }
    if (l == 0) {
        int i1 = 0; float b1 = acc[0];
#pragma unroll
        for (int e = 1; e < NE; e++) if (acc[e] > b1) { b1 = acc[e]; i1 = e; }
        int i2 = -1; float b2 = -1e30f;
#pragma unroll
        for (int e = 0; e < NE; e++) if (e != i1 && acc[e] > b2) { b2 = acc[e]; i2 = e; }
        float w1 = 1.0f / (1.0f + __expf(b2 - b1));   // exact renormalized top-2
        top_i[tok * 2] = i1; top_i[tok * 2 + 1] = i2;
        top_w[tok * 2] = w1; top_w[tok * 2 + 1] = 1.0f - w1;
        atomicAdd(&counts[i1], 1); atomicAdd(&counts[i2], 1);
    }
}

__global__ void prefix_kernel(const int* __restrict__ counts,
                              int* __restrict__ offsets, int* __restrict__ cursor)
{
    if (threadIdx.x == 0 && blockIdx.x == 0) {
        int s = 0;
        for (int e = 0; e < NE; e++) { offsets[e] = s; cursor[e] = s; s += counts[e]; }
        offsets[NE] = s;
    }
}

__global__ __launch_bounds__(256) void scatter_kernel(
    const int* __restrict__ top_i,
    int* __restrict__ cursor, int* __restrict__ pair_tok, int* __restrict__ inv_pos)
{
    int tok = blockIdx.x * 256 + threadIdx.x;
    if (tok < T_TOK) {
#pragma unroll
        for (int k = 0; k < 2; k++) {
            int e = top_i[tok * 2 + k];
            int pos = atomicAdd(&cursor[e], 1);
            pair_tok[pos] = tok;
            inv_pos[tok * 2 + k] = pos;
        }
    }
}

// ---------------- x f32 -> bf16 ----------------
__global__ __launch_bounds__(256) void cvt_x_kernel(const float* __restrict__ x,
                                                    unsigned short* __restrict__ xbf)
{
    int i = blockIdx.x * 256 + threadIdx.x;
    float4 v = ((const float4*)x)[i];
    ushort4 o;
    o.x = f2bf(v.x); o.y = f2bf(v.y); o.z = f2bf(v.z); o.w = f2bf(v.w);
    ((ushort4*)xbf)[i] = o;
}

// ---------------- batched transpose+cvt: in[e][R][C] f32 -> out[e][C][R] bf16 (64x64 tiles) ----------------
__global__ __launch_bounds__(256) void transpose_cvt64(
    const float* __restrict__ in, unsigned short* __restrict__ outp, int R, int C)
{
    __shared__ float tile[64][65];
    const int e = blockIdx.z;
    const float* inp = in + (size_t)e * R * C;
    unsigned short* oute = outp + (size_t)e * R * C;
    const int c0 = blockIdx.x * 64, r0 = blockIdx.y * 64;
    const int lc = threadIdx.x & 63, lr = threadIdx.x >> 6;
#pragma unroll
    for (int i = 0; i < 16; ++i) {
        int r = lr + i * 4;
        tile[r][lc] = inp[(size_t)(r0 + r) * C + c0 + lc];
    }
    __syncthreads();
#pragma unroll
    for (int q = 0; q < 4; ++q) {
        int oc = (threadIdx.x >> 4) + q * 16;
        int j  = threadIdx.x & 15;
        ushort4 v;
        v.x = f2bf(tile[j * 4 + 0][oc]);
        v.y = f2bf(tile[j * 4 + 1][oc]);
        v.z = f2bf(tile[j * 4 + 2][oc]);
        v.w = f2bf(tile[j * 4 + 3][oc]);
        *(ushort4*)&oute[(size_t)(c0 + oc) * R + r0 + j * 4] = v;
    }
}

// ---------------- GEMM1: pipelined 256x128 tile, fused gate+up, counted vmcnt ----------------
// A = gathered x rows [pairs][H] bf16, B = wgT/wuT [E][F][H] bf16.
// LDS per buf: A 256x64 (32KB) + G 128x64 (16KB) + U 128x64 (16KB) = 64KB; dbuf = 128KB.
// Swizzle: 16B-chunk c within 128B row stored at c^(row&7); inverse applied on global src.
__global__ __launch_bounds__(512, 2) void gemm1_pipe(
    const unsigned short* __restrict__ xbf,
    const unsigned short* __restrict__ wgT,
    const unsigned short* __restrict__ wuT,
    const int* __restrict__ pair_tok, const int* __restrict__ offsets,
    unsigned short* __restrict__ Abuf)
{
    const int e = blockIdx.z;
    const int off = offsets[e], Ne = offsets[e + 1] - off;
    const int m0 = blockIdx.y * 256;
    if (m0 >= Ne) return;
    const int bn0 = blockIdx.x * 128;

    __shared__ char smem[131072];

    const int tid = threadIdx.x, l = tid & 63, w = tid >> 6;
    const int llo = l & 15, lhi = l >> 4;
    const int wm = w >> 2, wn = w & 3;
    const int lr = l >> 3, lc = l & 7;     // staging: row-in-8, 16B chunk

    // per-lane global sources for the 8 staging rounds (inverse-swizzled chunk)
    const unsigned short* src[8];
#pragma unroll
    for (int r = 0; r < 4; ++r) {          // A rows 0..255
        int row = r * 64 + w * 8 + lr;
        int pr = m0 + row; if (pr > Ne - 1) pr = Ne - 1;
        int tok = pair_tok[off + pr];
        src[r] = xbf + (size_t)tok * H_DIM + (lc ^ (row & 7)) * 8;
    }
#pragma unroll
    for (int r = 4; r < 6; ++r) {          // G rows 0..127
        int fr = (r - 4) * 64 + w * 8 + lr;
        src[r] = wgT + ((size_t)e * F_DIM + bn0 + fr) * H_DIM + (lc ^ (fr & 7)) * 8;
    }
#pragma unroll
    for (int r = 6; r < 8; ++r) {          // U rows 0..127
        int fr = (r - 6) * 64 + w * 8 + lr;
        src[r] = wuT + ((size_t)e * F_DIM + bn0 + fr) * H_DIM + (lc ^ (fr & 7)) * 8;
    }

    auto STAGE = [&](int tile, int b) {
#pragma unroll
        for (int r = 0; r < 8; ++r)
            gload_lds16(src[r] + tile * 64, smem + b * 65536 + r * 8192 + w * 1024);
    };

    STAGE(0, 0);
    STAGE(1, 1);

    f32x4 accG[8][2] = {}, accU[8][2] = {};
    const int NT = H_DIM / 64;   // 16

    for (int tt = 0; tt < NT; ++tt) {
        if (tt < NT - 1) { asm volatile("s_waitcnt vmcnt(8)" ::: "memory"); }
        else             { asm volatile("s_waitcnt vmcnt(0)" ::: "memory"); }
        __builtin_amdgcn_s_barrier();
        asm volatile("" ::: "memory");
        __builtin_amdgcn_sched_barrier(0);
        const char* base = smem + (tt & 1) * 65536;

        bf16x8 gfr[2][2], ufr[2][2];
#pragma unroll
        for (int n = 0; n < 2; ++n)
#pragma unroll
            for (int k2 = 0; k2 < 2; ++k2) {
                int fr = wn * 32 + n * 16 + llo;
                int c = k2 * 4 + lhi;
                gfr[n][k2] = *(const bf16x8*)(base + 32768 + fr * 128 + ((c ^ (fr & 7)) * 16));
                ufr[n][k2] = *(const bf16x8*)(base + 49152 + fr * 128 + ((c ^ (fr & 7)) * 16));
            }
        __builtin_amdgcn_s_setprio(1);
#pragma unroll
        for (int m = 0; m < 8; ++m) {
            int arow = wm * 128 + m * 16 + llo;
            int swz = arow & 7;
            bf16x8 a0 = *(const bf16x8*)(base + arow * 128 + ((lhi ^ swz) * 16));
            bf16x8 a1 = *(const bf16x8*)(base + arow * 128 + (((4 + lhi) ^ swz) * 16));
#pragma unroll
            for (int n = 0; n < 2; ++n) {
                accG[m][n] = __builtin_amdgcn_mfma_f32_16x16x32_bf16(a0, gfr[n][0], accG[m][n], 0, 0, 0);
                accG[m][n] = __builtin_amdgcn_mfma_f32_16x16x32_bf16(a1, gfr[n][1], accG[m][n], 0, 0, 0);
                accU[m][n] = __builtin_amdgcn_mfma_f32_16x16x32_bf16(a0, ufr[n][0], accU[m][n], 0, 0, 0);
                accU[m][n] = __builtin_amdgcn_mfma_f32_16x16x32_bf16(a1, ufr[n][1], accU[m][n], 0, 0, 0);
            }
        }
        __builtin_amdgcn_s_setprio(0);
        asm volatile("s_waitcnt lgkmcnt(0)" ::: "memory");
        __builtin_amdgcn_sched_barrier(0);
        __builtin_amdgcn_s_barrier();
        asm volatile("" ::: "memory");
        __builtin_amdgcn_sched_barrier(0);
        if (tt + 2 < NT) STAGE(tt + 2, tt & 1);
    }

    // epilogue: silu(g)*u -> bf16. C/D: col=lane&15, row=(lane>>4)*4+reg
#pragma unroll
    for (int m = 0; m < 8; ++m) {
#pragma unroll
        for (int r = 0; r < 4; ++r) {
            int grow = m0 + wm * 128 + m * 16 + lhi * 4 + r;
            if (grow < Ne) {
                size_t p = (size_t)(off + grow);
#pragma unroll
                for (int n = 0; n < 2; ++n) {
                    float g = accG[m][n][r], u = accU[m][n][r];
                    float a = g / (1.0f + __expf(-g)) * u;
                    Abuf[p * F_DIM + bn0 + wn * 32 + n * 16 + llo] = f2bf(a);
                }
            }
        }
    }
}

// ---------------- GEMM2: pipelined 128x256 tile, writes per-pair f32 rows (no atomics) ----------------
// A = Abuf [pairs][F] bf16, B = wdT [E][H][F] bf16. LDS per buf: A 16KB + B 32KB = 48KB; dbuf 96KB.
__global__ __launch_bounds__(512, 2) void gemm2_pipe(
    const unsigned short* __restrict__ Abuf,
    const unsigned short* __restrict__ wdT,
    const int* __restrict__ offsets,
    float* __restrict__ dbuf)
{
    const int e = blockIdx.z;
    const int off = offsets[e], Ne = offsets[e + 1] - off;
    const int m0 = blockIdx.y * 128;
    if (m0 >= Ne) return;
    const int bn0 = blockIdx.x * 256;

    __shared__ char smem[98304];

    const int tid = threadIdx.x, l = tid & 63, w = tid >> 6;
    const int llo = l & 15, lhi = l >> 4;
    const int wm = w >> 2, wn = w & 3;
    const int lr = l >> 3, lc = l & 7;

    const unsigned short* src[6];
#pragma unroll
    for (int r = 0; r < 2; ++r) {          // A rows 0..127
        int row = r * 64 + w * 8 + lr;
        int pr = m0 + row; if (pr > Ne - 1) pr = Ne - 1;
        src[r] = Abuf + (size_t)(off + pr) * F_DIM + (lc ^ (row & 7)) * 8;
    }
#pragma unroll
    for (int r = 2; r < 6; ++r) {          // B rows 0..255 (h index)
        int hr = (r - 2) * 64 + w * 8 + lr;
        src[r] = wdT + ((size_t)e * H_DIM + bn0 + hr) * F_DIM + (lc ^ (hr & 7)) * 8;
    }

    auto STAGE = [&](int tile, int b) {
#pragma unroll
        for (int r = 0; r < 6; ++r)
            gload_lds16(src[r] + tile * 64, smem + b * 49152 + r * 8192 + w * 1024);
    };

    STAGE(0, 0);
    STAGE(1, 1);

    f32x4 acc[4][4] = {};
    const int NT = F_DIM / 64;   // 44

    for (int tt = 0; tt < NT; ++tt) {
        if (tt < NT - 1) { asm volatile("s_waitcnt vmcnt(6)" ::: "memory"); }
        else             { asm volatile("s_waitcnt vmcnt(0)" ::: "memory"); }
        __builtin_amdgcn_s_barrier();
        asm volatile("" ::: "memory");
        __builtin_amdgcn_sched_barrier(0);
        const char* base = smem + (tt & 1) * 49152;

        bf16x8 bfr[4][2];
#pragma unroll
        for (int n = 0; n < 4; ++n)
#pragma unroll
            for (int k2 = 0; k2 < 2; ++k2) {
                int hr = wn * 64 + n * 16 + llo;
                int c = k2 * 4 + lhi;
                bfr[n][k2] = *(const bf16x8*)(base + 16384 + hr * 128 + ((c ^ (hr & 7)) * 16));
            }
        __builtin_amdgcn_s_setprio(1);
#pragma unroll
        for (int m = 0; m < 4; ++m) {
            int arow = wm * 64 + m * 16 + llo;
            int swz = arow & 7;
            bf16x8 a0 = *(const bf16x8*)(base + arow * 128 + ((lhi ^ swz) * 16));
            bf16x8 a1 = *(const bf16x8*)(base + arow * 128 + (((4 + lhi) ^ swz) * 16));
#pragma unroll
            for (int n = 0; n < 4; ++n) {
                acc[m][n] = __builtin_amdgcn_mfma_f32_16x16x32_bf16(a0, bfr[n][0], acc[m][n], 0, 0, 0);
                acc[m][n] = __builtin_amdgcn_mfma_f32_16x16x32_bf16(a1, bfr[n][1], acc[m][n], 0, 0, 0);
            }
        }
        __builtin_amdgcn_s_setprio(0);
        asm volatile("s_waitcnt lgkmcnt(0)" ::: "memory");
        __builtin_amdgcn_sched_barrier(0);
        __builtin_amdgcn_s_barrier();
        asm volatile("" ::: "memory");
        __builtin_amdgcn_sched_barrier(0);
        if (tt + 2 < NT) STAGE(tt + 2, tt & 1);
    }

#pragma unroll
    for (int m = 0; m < 4; ++m) {
#pragma unroll
        for (int r = 0; r < 4; ++r) {
            int grow = m0 + wm * 64 + m * 16 + lhi * 4 + r;
            if (grow < Ne) {
                size_t p = (size_t)(off + grow);
#pragma unroll
                for (int n = 0; n < 4; ++n)
                    dbuf[p * H_DIM + bn0 + wn * 64 + n * 16 + llo] = acc[m][n][r];
            }
        }
    }
}

// ---------------- combine: out[t] = w0*d[p0] + w1*d[p1] ----------------
__global__ __launch_bounds__(256) void combine_kernel(
    const float* __restrict__ dbuf, const int* __restrict__ inv_pos,
    const float* __restrict__ top_w, float* __restrict__ out)
{
    int tok = blockIdx.x;
    int p0 = inv_pos[tok * 2], p1 = inv_pos[tok * 2 + 1];
    float w0 = top_w[tok * 2], w1 = top_w[tok * 2 + 1];
    int c = threadIdx.x * 4;
    float4 a = *(const float4*)&dbuf[(size_t)p0 * H_DIM + c];
    float4 b = *(const float4*)&dbuf[(size_t)p1 * H_DIM + c];
    float4 o;
    o.x = w0 * a.x + w1 * b.x;
    o.y = w0 * a.y + w1 * b.y;
    o.z = w0 * a.z + w1 * b.z;
    o.w = w0 * a.w + w1 * b.w;
    *(float4*)&out[(size_t)tok * H_DIM + c] = o;
}

extern "C" void kernel_launch(void* const* d_in, const int* in_sizes, int n_in,
                              void* d_out, int out_size, void* d_ws, size_t ws_size,
                              hipStream_t stream)
{
    const float* x  = (const float*)d_in[0];
    const float* wr = (const float*)d_in[1];
    const float* wg = (const float*)d_in[2];
    const float* wu = (const float*)d_in[3];
    const float* wd = (const float*)d_in[4];
    float* out = (float*)d_out;

    char* ws = (char*)d_ws;
    const size_t WT = (size_t)NE * F_DIM * H_DIM * 2;            // 46,137,344 B
    unsigned short* wgT  = (unsigned short*)(ws);                // reused as wdT after gemm1
    unsigned short* wuT  = (unsigned short*)(ws + WT);           // reused as dbuf (f32, 33.5MB) after gemm1
    unsigned short* Abuf = (unsigned short*)(ws + 2 * WT);
    unsigned short* xbf  = (unsigned short*)(ws + 3 * WT);
    char* misc = ws + 3 * WT + (size_t)T_TOK * H_DIM * 2;
    int*   pair_tok = (int*)(misc);
    int*   top_i    = (int*)(misc + 32768);
    float* top_w    = (float*)(misc + 65536);
    int*   inv_pos  = (int*)(misc + 98304);
    int*   counts   = (int*)(misc + 131072);
    int*   offsets  = counts + 8;
    int*   cursor   = offsets + 9;
    unsigned short* wdT = wgT;
    float* dbuf = (float*)wuT;

    hipMemsetAsync(counts, 0, 8 * sizeof(int), stream);

    cvt_x_kernel<<<T_TOK * H_DIM / (256 * 4), 256, 0, stream>>>(x, xbf);
    transpose_cvt64<<<dim3(F_DIM / 64, H_DIM / 64, NE), 256, 0, stream>>>(wg, wgT, H_DIM, F_DIM);
    transpose_cvt64<<<dim3(F_DIM / 64, H_DIM / 64, NE), 256, 0, stream>>>(wu, wuT, H_DIM, F_DIM);
    router_kernel<<<T_TOK / 4, 256, 0, stream>>>(x, wr, top_i, top_w, counts);
    prefix_kernel<<<1, 64, 0, stream>>>(counts, offsets, cursor);
    scatter_kernel<<<T_TOK / 256, 256, 0, stream>>>(top_i, cursor, pair_tok, inv_pos);
    gemm1_pipe<<<dim3(F_DIM / 128, 32, NE), 512, 0, stream>>>(xbf, wgT, wuT, pair_tok, offsets, Abuf);
    transpose_cvt64<<<dim3(H_DIM / 64, F_DIM / 64, NE), 256, 0, stream>>>(wd, wdT, F_DIM, H_DIM);
    gemm2_pipe<<<dim3(H_DIM / 256, 64, NE), 512, 0, stream>>>(Abuf, wdT, offsets, dbuf);
    combine_kernel<<<T_TOK, 256, 0, stream>>>(dbuf, inv_pos, top_w, out);
}